// Round 1
// 703.920 us; speedup vs baseline: 1.0375x; 1.0375x over previous
//
#include <hip/hip_runtime.h>
#include <cstdint>

namespace {
constexpr int kN = 50000;          // nodes per encoder
constexpr int kE = 200000;         // directed edges per encoder (pre self-loop)
constexpr int kE2 = kE + kN;       // with self loops (per encoder)
constexpr int kG = 256;            // graphs per encoder
constexpr float kNegSlope = 0.2f;
}

using half8   = __attribute__((ext_vector_type(8))) _Float16;
using floatx4 = __attribute__((ext_vector_type(4))) float;

__device__ __forceinline__ void gld_lds16(const void* g, void* l) {
  __builtin_amdgcn_global_load_lds(
      (const __attribute__((address_space(1))) unsigned int*)g,
      (__attribute__((address_space(3))) unsigned int*)l, 16, 0, 0);
}

// fast exp: e^x = 2^(x*log2(e)) via hardware v_exp_f32 (no libm call)
__device__ __forceinline__ float fexp(float x) {
  return __builtin_amdgcn_exp2f(x * 1.44269504088896f);
}

// ---------------- fp16 MFMA GEMM: C[M,N] = A[M,K] @ B[K,N] -----------
// Single-product fp16 (fp32 accumulate). A row-major f16 [M,K]; B
// pre-transposed f16 [N,K]. 128x128 tile, BK=32, 256 threads = 4 waves.
// NT=4: XCD-aware swizzle — blocks land on XCD (id%8); giving row-tile
// r=(s>>2)*8+(id&7), col=s&3 (s=id>>3) puts all 4 col-tiles of a row on
// ONE XCD so A is filled into one L2 once.
// R13: double-buffered LDS (2x16KB) + raw s_barrier + counted
// s_waitcnt vmcnt(4) — next tile's global_load_lds stays in flight
// across the barrier instead of the __syncthreads vmcnt(0) drain that
// exposed staging latency every K-step (MfmaUtil was 17.5%).
template <int OUTF16, int NT>
__global__ __launch_bounds__(256, 4) void gemm_f16(
    const _Float16* __restrict__ A, const _Float16* __restrict__ B,
    void* __restrict__ Cv, int M, int N, int K) {
  __shared__ alignas(16) char smem[32768];  // [buf][A:8K|B:8K]
  const int t = threadIdx.x;
  const int w = t >> 6;
  const int l = t & 63;
  int bm, bn;
  if constexpr (NT == 1) {
    bm = blockIdx.x * 128;
    bn = 0;
  } else {  // NT == 4
    const int x = blockIdx.x & 7;
    const int s = blockIdx.x >> 3;
    bm = (((s >> 2) << 3) + x) * 128;
    bn = (s & 3) * 128;
    if (bm >= M) return;  // padded row-tiles (whole block exits: no barrier)
  }
  const int wm = (w & 1) * 64;
  const int wn = (w >> 1) * 64;
  const int quad = l >> 4;
  const int lrow = l & 15;

  floatx4 acc[4][4];
#pragma unroll
  for (int mi = 0; mi < 4; ++mi)
#pragma unroll
    for (int ni = 0; ni < 4; ++ni) acc[mi][ni] = (floatx4){0.f, 0.f, 0.f, 0.f};

  // stage one 128x32 A-tile + B-tile into the given LDS buffer (4 loads/thread)
  auto stage = [&](char* sbuf, int k0) {
#pragma unroll
    for (int j = 0; j < 2; ++j) {
      const int s = w * 128 + j * 64 + l;          // slot id 0..511
      const int row = ((s >> 6) << 4) + (s & 15);  // 0..127
      const int q = (s >> 4) & 3;
      int ga = bm + row;
      ga = (ga < M) ? ga : (M - 1);                // clamp: keep lanes active
      gld_lds16(A + (size_t)ga * K + k0 + q * 8, sbuf + s * 16);
      gld_lds16(B + (size_t)(bn + row) * K + k0 + q * 8, sbuf + 8192 + s * 16);
    }
  };

  stage(smem, 0);  // prologue: 4 loads in flight
  int cur = 0;
  for (int k0 = 0; k0 < K; k0 += 32) {
    char* sA = smem + cur * 16384;
    char* sB = sA + 8192;
    if (k0 + 32 < K) {
      stage(smem + ((cur ^ 1) * 16384), k0 + 32);  // 4 more in flight (8 total)
      asm volatile("s_waitcnt vmcnt(4)" ::: "memory");  // cur's 4 have landed
    } else {
      asm volatile("s_waitcnt vmcnt(0)" ::: "memory");  // last tile: drain
    }
    __builtin_amdgcn_s_barrier();        // all waves: buf[cur] ready
    asm volatile("" ::: "memory");       // fence: keep ds_reads below barrier
    half8 fa[4], fb[4];
#pragma unroll
    for (int mi = 0; mi < 4; ++mi)
      fa[mi] = *(const half8*)(sA + ((wm >> 4) + mi) * 1024 + l * 16);
#pragma unroll
    for (int ni = 0; ni < 4; ++ni)
      fb[ni] = *(const half8*)(sB + ((wn >> 4) + ni) * 1024 + l * 16);
#pragma unroll
    for (int mi = 0; mi < 4; ++mi)
#pragma unroll
      for (int ni = 0; ni < 4; ++ni)
        acc[mi][ni] = __builtin_amdgcn_mfma_f32_16x16x32_f16(fa[mi], fb[ni],
                                                             acc[mi][ni], 0, 0, 0);
    asm volatile("" ::: "memory");       // fence: ds_reads done before barrier
    __builtin_amdgcn_s_barrier();        // buf[cur] free for re-staging
    cur ^= 1;
  }
  // epilogue: C/D layout col=lane&15, row=quad*4+reg
  const int colbase = bn + wn + lrow;
#pragma unroll
  for (int mi = 0; mi < 4; ++mi) {
    const int rbase = bm + wm + mi * 16 + quad * 4;
#pragma unroll
    for (int r = 0; r < 4; ++r) {
      const int grow = rbase + r;
      if (grow < M) {
        if constexpr (OUTF16) {
          _Float16* C = (_Float16*)Cv;
#pragma unroll
          for (int ni = 0; ni < 4; ++ni)
            C[(size_t)grow * N + colbase + ni * 16] = (_Float16)acc[mi][ni][r];
        } else {
          float* C = (float*)Cv;
#pragma unroll
          for (int ni = 0; ni < 4; ++ni)
            C[(size_t)grow * N + colbase + ni * 16] = acc[mi][ni][r];
        }
      }
    }
  }
}

// ------- all three weight transposes + f16 casts in one kernel --------
__global__ void wt_split_all(const float* __restrict__ W1, _Float16* Th1,
                             const float* __restrict__ W2, _Float16* Th2,
                             const float* __restrict__ W3, _Float16* Th3) {
  int idx = blockIdx.x * blockDim.x + threadIdx.x;
  const float* W;
  _Float16* Th;
  int K, N;
  if (idx < 64 * 512) {
    W = W1; Th = Th1; K = 64; N = 512;
  } else if (idx < 64 * 512 + 512 * 512) {
    idx -= 64 * 512;
    W = W2; Th = Th2; K = 512; N = 512;
  } else if (idx < 64 * 512 + 512 * 512 + 512 * 128) {
    idx -= 64 * 512 + 512 * 512;
    W = W3; Th = Th3; K = 512; N = 128;
  } else {
    return;
  }
  const int k = idx / N;
  const int n = idx - k * N;
  Th[n * K + k] = (_Float16)W[idx];
}

// ------- combined prep: both x casts + cnt=1 (2N) + total=0 -----------
__global__ void prep2(const float* __restrict__ x0, const float* __restrict__ x1,
                      _Float16* __restrict__ Xh, int* __restrict__ cnt,
                      int* __restrict__ total) {
  const int idx = blockIdx.x * blockDim.x + threadIdx.x;
  const int half = kN * 64;
  if (idx < half) Xh[idx] = (_Float16)x0[idx];
  else if (idx < 2 * half) Xh[idx] = (_Float16)x1[idx - half];
  if (idx < 2 * kN) cnt[idx] = 1;  // the self loop
  if (idx == 0) *total = 0;
}
// ------- single-encoder prep (fallback path) --------------------------
__global__ void prep(const float* __restrict__ X, _Float16* __restrict__ Xh,
                     int* __restrict__ cnt, int* __restrict__ total, int nsplit,
                     int n) {
  const int idx = blockIdx.x * blockDim.x + threadIdx.x;
  if (idx < nsplit) Xh[idx] = (_Float16)X[idx];
  if (idx < n) cnt[idx] = 1;
  if (idx == 0) *total = 0;
}

// ---------------- CSR (by dst) build ----------------------------------
__global__ void count_edges2(const int* __restrict__ d0, const int* __restrict__ d1,
                             int* __restrict__ cnt) {
  const int i = blockIdx.x * blockDim.x + threadIdx.x;
  if (i < kE) atomicAdd(&cnt[d0[i]], 1);
  else if (i < 2 * kE) atomicAdd(&cnt[d1[i - kE] + kN], 1);
}
__global__ void fill_edges2(const int* __restrict__ s0, const int* __restrict__ d0,
                            const int* __restrict__ s1, const int* __restrict__ d1,
                            int* __restrict__ cursor, int* __restrict__ csr) {
  const int i = blockIdx.x * blockDim.x + threadIdx.x;
  if (i < kE) {
    const int p = atomicAdd(&cursor[d0[i]], 1);
    csr[p] = s0[i];
  } else if (i < 2 * kE) {
    const int j = i - kE;
    const int p = atomicAdd(&cursor[d1[j] + kN], 1);
    csr[p] = s1[j] + kN;
  }
}
__global__ void count_edges(const int* __restrict__ dst, int* __restrict__ cnt,
                            int ne) {
  const int i = blockIdx.x * blockDim.x + threadIdx.x;
  if (i < ne) atomicAdd(&cnt[dst[i]], 1);
}
__global__ void fill_edges(const int* __restrict__ src, const int* __restrict__ dst,
                           int* __restrict__ cursor, int* __restrict__ csr, int ne) {
  const int i = blockIdx.x * blockDim.x + threadIdx.x;
  if (i < ne) {
    const int p = atomicAdd(&cursor[dst[i]], 1);
    csr[p] = src[i];
  }
}
__global__ void alloc_ranges(const int* __restrict__ cnt, int* __restrict__ start,
                             int* __restrict__ cursor, int* __restrict__ total,
                             int* __restrict__ csr, int n) {
  const int i = blockIdx.x * blockDim.x + threadIdx.x;
  const int lane = threadIdx.x & 63;
  const int v = (i < n) ? cnt[i] : 0;
  int sc = v;
#pragma unroll
  for (int off = 1; off < 64; off <<= 1) {
    const int t = __shfl_up(sc, off);
    if (lane >= off) sc += t;
  }
  const int wtot = __shfl(sc, 63);
  int base = 0;
  if (lane == 63) base = atomicAdd(total, wtot);
  base = __shfl(base, 63);
  const int st = base + sc - v;
  if (i < n) {
    start[i] = st;
    cursor[i] = st + 1;
    csr[st] = i;  // self loop first
  }
}

// ---------------- GAT aggregate, layers 1-2 (f16 h) -------------------
// R13: attention dots fused in. The gather already has h[src] in regs;
// <h[src],a_src> is 8 FMA + 4 shfl_xor within the 16-lane head group,
// and <h[node],a_dst> comes from the self-loop gather (CSR entry 0).
// This deletes the node_alpha8 pass (full re-read of h, ~102 MB/layer).
__global__ void gat_agg4(const _Float16* __restrict__ h,
                         const float* __restrict__ a_src,
                         const float* __restrict__ a_dst,
                         const int* __restrict__ start, const int* __restrict__ cnt,
                         const int* __restrict__ csr_src,
                         const float* __restrict__ bias,
                         _Float16* __restrict__ outH, int n_nodes) {
  const int gtid = blockIdx.x * blockDim.x + threadIdx.x;
  const int node = gtid >> 6;
  const int lane = threadIdx.x & 63;
  if (node >= n_nodes) return;
  const int ch = lane * 8;
  float as_r[8], ad_r[8];
#pragma unroll
  for (int j = 0; j < 8; ++j) {
    as_r[j] = a_src[ch + j];
    ad_r[j] = a_dst[ch + j];
  }
  const int s = start[node];
  const int c = cnt[node];
  // self loop first (csr_src[s] == node): gives both dst-dot and its edge
  const half8 vs = *(const half8*)(h + (size_t)node * 512 + ch);
  float fs[8];
  float t_src = 0.f, t_dst = 0.f;
#pragma unroll
  for (int j = 0; j < 8; ++j) {
    fs[j] = (float)vs[j];
    t_src = fmaf(fs[j], as_r[j], t_src);
    t_dst = fmaf(fs[j], ad_r[j], t_dst);
  }
#pragma unroll
  for (int off = 1; off < 16; off <<= 1) {
    t_src += __shfl_xor(t_src, off);
    t_dst += __shfl_xor(t_dst, off);
  }
  const float ad = t_dst;  // <h[node], a_dst> for this head
  float es = t_src + ad;
  es = (es > 0.f) ? es : kNegSlope * es;
  const float ws = fexp(es);
  float d0 = ws, d1 = 0.f;
  float a0[8], a1[8];
#pragma unroll
  for (int j = 0; j < 8; ++j) {
    a0[j] = ws * fs[j];
    a1[j] = 0.f;
  }
  int i = 1;
  for (; i + 2 <= c; i += 2) {
    const int s0 = csr_src[s + i];
    const int s1 = csr_src[s + i + 1];
    const half8 v0 = *(const half8*)(h + (size_t)s0 * 512 + ch);
    const half8 v1 = *(const half8*)(h + (size_t)s1 * 512 + ch);
    float f0[8], f1[8];
    float t0 = 0.f, t1 = 0.f;
#pragma unroll
    for (int j = 0; j < 8; ++j) {
      f0[j] = (float)v0[j];
      f1[j] = (float)v1[j];
      t0 = fmaf(f0[j], as_r[j], t0);
      t1 = fmaf(f1[j], as_r[j], t1);
    }
#pragma unroll
    for (int off = 1; off < 16; off <<= 1) {
      t0 += __shfl_xor(t0, off);
      t1 += __shfl_xor(t1, off);
    }
    float e0 = t0 + ad;
    float e1 = t1 + ad;
    e0 = (e0 > 0.f) ? e0 : kNegSlope * e0;
    e1 = (e1 > 0.f) ? e1 : kNegSlope * e1;
    const float w0 = fexp(e0);
    const float w1 = fexp(e1);
    d0 += w0;
    d1 += w1;
#pragma unroll
    for (int j = 0; j < 8; ++j) {
      a0[j] = fmaf(w0, f0[j], a0[j]);
      a1[j] = fmaf(w1, f1[j], a1[j]);
    }
  }
  if (i < c) {
    const int s0 = csr_src[s + i];
    const half8 v0 = *(const half8*)(h + (size_t)s0 * 512 + ch);
    float f0[8];
    float t0 = 0.f;
#pragma unroll
    for (int j = 0; j < 8; ++j) {
      f0[j] = (float)v0[j];
      t0 = fmaf(f0[j], as_r[j], t0);
    }
#pragma unroll
    for (int off = 1; off < 16; off <<= 1) t0 += __shfl_xor(t0, off);
    float e0 = t0 + ad;
    e0 = (e0 > 0.f) ? e0 : kNegSlope * e0;
    const float w0 = fexp(e0);
    d0 += w0;
#pragma unroll
    for (int j = 0; j < 8; ++j) a0[j] = fmaf(w0, f0[j], a0[j]);
  }
  const float inv = 1.f / (d0 + d1 + 1e-16f);
  half8 H;
#pragma unroll
  for (int j = 0; j < 8; ++j) {
    float v = (a0[j] + a1[j]) * inv + bias[ch + j];
    v = (v > 0.f) ? v : (fexp(v) - 1.f);  // elu via hw exp
    H[j] = (_Float16)v;
  }
  *(half8*)(outH + (size_t)node * 512 + ch) = H;
}

// ---------- GAT aggregate, layer 3 (H=1, fp32, fused dots) ------------
__global__ void gat_agg_l3(const float* __restrict__ h,
                           const float* __restrict__ a_src,
                           const float* __restrict__ a_dst,
                           const int* __restrict__ start, const int* __restrict__ cnt,
                           const int* __restrict__ csr_src,
                           const float* __restrict__ bias,
                           float* __restrict__ out, int n_nodes) {
  const int gtid = blockIdx.x * blockDim.x + threadIdx.x;
  const int node = gtid >> 6;
  const int lane = threadIdx.x & 63;
  if (node >= n_nodes) return;
  const float2 asv = *(const float2*)(a_src + lane * 2);
  const float2 adv = *(const float2*)(a_dst + lane * 2);
  const int s = start[node];
  const int c = cnt[node];
  // self loop first: dst-dot + its own edge
  const float2 vs = *(const float2*)(h + (size_t)node * 128 + lane * 2);
  float t_src = fmaf(vs.x, asv.x, vs.y * asv.y);
  float t_dst = fmaf(vs.x, adv.x, vs.y * adv.y);
#pragma unroll
  for (int off = 1; off < 64; off <<= 1) {
    t_src += __shfl_xor(t_src, off);
    t_dst += __shfl_xor(t_dst, off);
  }
  const float ad = t_dst;
  float es = t_src + ad;
  es = (es > 0.f) ? es : kNegSlope * es;
  const float ws = fexp(es);
  float2 a0 = make_float2(ws * vs.x, ws * vs.y);
  float2 a1 = make_float2(0.f, 0.f);
  float d0 = ws, d1 = 0.f;
  int i = 1;
  for (; i + 2 <= c; i += 2) {
    const int s0 = csr_src[s + i];
    const int s1 = csr_src[s + i + 1];
    const float2 v0 = *(const float2*)(h + (size_t)s0 * 128 + lane * 2);
    const float2 v1 = *(const float2*)(h + (size_t)s1 * 128 + lane * 2);
    float t0 = fmaf(v0.x, asv.x, v0.y * asv.y);
    float t1 = fmaf(v1.x, asv.x, v1.y * asv.y);
#pragma unroll
    for (int off = 1; off < 64; off <<= 1) {
      t0 += __shfl_xor(t0, off);
      t1 += __shfl_xor(t1, off);
    }
    float e0 = t0 + ad;
    float e1 = t1 + ad;
    e0 = (e0 > 0.f) ? e0 : kNegSlope * e0;
    e1 = (e1 > 0.f) ? e1 : kNegSlope * e1;
    const float w0 = fexp(e0);
    const float w1 = fexp(e1);
    d0 += w0;
    d1 += w1;
    a0.x = fmaf(w0, v0.x, a0.x); a1.x = fmaf(w1, v1.x, a1.x);
    a0.y = fmaf(w0, v0.y, a0.y); a1.y = fmaf(w1, v1.y, a1.y);
  }
  if (i < c) {
    const int s0 = csr_src[s + i];
    const float2 v0 = *(const float2*)(h + (size_t)s0 * 128 + lane * 2);
    float t0 = fmaf(v0.x, asv.x, v0.y * asv.y);
#pragma unroll
    for (int off = 1; off < 64; off <<= 1) t0 += __shfl_xor(t0, off);
    float e0 = t0 + ad;
    e0 = (e0 > 0.f) ? e0 : kNegSlope * e0;
    const float w0 = fexp(e0);
    d0 += w0;
    a0.x = fmaf(w0, v0.x, a0.x);
    a0.y = fmaf(w0, v0.y, a0.y);
  }
  const float inv = 1.f / (d0 + d1 + 1e-16f);
  *(float2*)(out + (size_t)node * 128 + lane * 2) =
      make_float2((a0.x + a1.x) * inv + bias[lane * 2],
                  (a0.y + a1.y) * inv + bias[lane * 2 + 1]);
}

// ---------------- global max pool over sorted batch -------------------
__global__ void pool_max(const float* __restrict__ x, const int* __restrict__ batch,
                         float* __restrict__ emb, int n_nodes) {
  __shared__ int lohi[2];
  const int g = blockIdx.x;
  if (threadIdx.x == 0) {
    int lo = 0, hi = n_nodes;
    while (lo < hi) {
      const int mid = (lo + hi) >> 1;
      if (batch[mid] < g) lo = mid + 1; else hi = mid;
    }
    lohi[0] = lo;
    hi = n_nodes;
    while (lo < hi) {
      const int mid = (lo + hi) >> 1;
      if (batch[mid] < g + 1) lo = mid + 1; else hi = mid;
    }
    lohi[1] = lo;
  }
  __syncthreads();
  const int lo = lohi[0], hi = lohi[1];
  const int c = threadIdx.x;  // 128 channels
  float m = -1e30f;
  for (int nid = lo; nid < hi; ++nid) m = fmaxf(m, x[(size_t)nid * 128 + c]);
  emb[g * 128 + c] = (lo < hi) ? m : 0.f;
}

// ---------------- final MLP head --------------------------------------
__global__ void mlp_head(const float* __restrict__ e1, const float* __restrict__ e2,
                         const float* __restrict__ mw1, const float* __restrict__ mb1,
                         const float* __restrict__ mw2, const float* __restrict__ mb2,
                         float* __restrict__ out) {
  __shared__ float z[256];
  __shared__ float red[128];
  const int g = blockIdx.x;
  const int j = threadIdx.x;  // 128
  z[j] = e1[g * 128 + j];
  z[j + 128] = e2[g * 128 + j];
  __syncthreads();
  float acc = mb1[j];
  for (int k = 0; k < 256; ++k) acc = fmaf(z[k], mw1[k * 128 + j], acc);
  acc = fmaxf(acc, 0.f) * mw2[j];
  red[j] = acc;
  __syncthreads();
  for (int s = 64; s > 0; s >>= 1) {
    if (j < s) red[j] += red[j + s];
    __syncthreads();
  }
  if (j == 0) out[g] = red[0] + mb2[0];
}

// ---------------- launcher --------------------------------------------
namespace {
struct Bufs {
  _Float16 *R1h, *R2h;
  float *R1f, *R2f, *asrc, *adst;
  int *cnt, *start, *cursor, *csr, *total;
  _Float16 *Wth1, *Wth2, *Wth3;
  float* emb;
  size_t need;
};

Bufs plan(void* d_ws, int M, int E) {
  Bufs b;
  char* w = (char*)d_ws;
  size_t off = 0;
  auto take = [&](size_t bytes) -> void* {
    void* p = w + off;
    off += (bytes + 255) & ~(size_t)255;
    return p;
  };
  b.R1h = (_Float16*)take((size_t)M * 512 * 2);  // f16 activations
  b.R1f = (float*)b.R1h;                         // layer-3 out alias [M,128]
  b.R2h = (_Float16*)take((size_t)M * 512 * 2);  // h f16; l3 fp32 alias
  b.R2f = (float*)b.R2h;
  b.asrc = (float*)take((size_t)M * 4 * 4);      // (unused since R13 fusion)
  b.adst = (float*)take((size_t)M * 4 * 4);
  b.cnt = (int*)take((size_t)M * 4);
  b.start = (int*)take((size_t)M * 4);
  b.cursor = (int*)take((size_t)M * 4);
  b.csr = (int*)take((size_t)E * 4);
  b.total = (int*)take(256);
  b.Wth1 = (_Float16*)take((size_t)64 * 512 * 2);
  b.Wth2 = (_Float16*)take((size_t)512 * 512 * 2);
  b.Wth3 = (_Float16*)take((size_t)512 * 128 * 2);
  b.emb = (float*)take((size_t)2 * kG * 128 * 4);
  b.need = off;
  return b;
}

void run_layers(const Bufs& b, void* const* d_in, int M, hipStream_t stream) {
  const float* as1 = (const float*)d_in[7];
  const float* ad1 = (const float*)d_in[8];
  const float* b1 = (const float*)d_in[9];
  const float* as2 = (const float*)d_in[11];
  const float* ad2 = (const float*)d_in[12];
  const float* b2 = (const float*)d_in[13];
  const float* as3 = (const float*)d_in[15];
  const float* ad3 = (const float*)d_in[16];
  const float* b3 = (const float*)d_in[17];
  const int nodeBlocks = (M * 64) / 256;  // 1 wave/node
  const int MT = (M + 127) / 128;
  const int MTp = (MT + 7) & ~7;          // pad rows to multiple of 8 (XCD map)

  // layer 1: [M,64] @ [64,512], h -> f16 (A1h aliases R1h)
  gemm_f16<1, 4><<<MTp * 4, 256, 0, stream>>>(b.R1h, b.Wth1, b.R2h, M, 512, 64);
  gat_agg4<<<nodeBlocks, 256, 0, stream>>>(b.R2h, as1, ad1, b.start, b.cnt,
                                           b.csr, b1, b.R1h, M);
  // layer 2: [M,512] @ [512,512], h -> f16
  gemm_f16<1, 4><<<MTp * 4, 256, 0, stream>>>(b.R1h, b.Wth2, b.R2h, M, 512, 512);
  gat_agg4<<<nodeBlocks, 256, 0, stream>>>(b.R2h, as2, ad2, b.start, b.cnt,
                                           b.csr, b2, b.R1h, M);
  // layer 3: [M,512] @ [512,128], H=1, no elu, fp32 out
  gemm_f16<0, 1><<<MT, 256, 0, stream>>>(b.R1h, b.Wth3, b.R2f, M, 128, 512);
  gat_agg_l3<<<nodeBlocks, 256, 0, stream>>>(b.R2f, as3, ad3, b.start, b.cnt,
                                             b.csr, b3, b.R1f, M);
}
}  // namespace

extern "C" void kernel_launch(void* const* d_in, const int* in_sizes, int n_in,
                              void* d_out, int out_size, void* d_ws, size_t ws_size,
                              hipStream_t stream) {
  (void)in_sizes; (void)n_in; (void)out_size;
  const float* W1 = (const float*)d_in[6];
  const float* W2 = (const float*)d_in[10];
  const float* W3 = (const float*)d_in[14];
  const float* mw1 = (const float*)d_in[18];
  const float* mb1 = (const float*)d_in[19];
  const float* mw2 = (const float*)d_in[20];
  const float* mb2 = (const float*)d_in[21];

  // Prefer combined (both encoders batched, M=2N) if it fits the workspace.
  Bufs bc = plan(d_ws, 2 * kN, 2 * kE2);
  const bool combined = bc.need <= ws_size;
  Bufs b = combined ? bc : plan(d_ws, kN, kE2);

  const int wtot = 64 * 512 + 512 * 512 + 512 * 128;
  wt_split_all<<<(wtot + 255) / 256, 256, 0, stream>>>(W1, b.Wth1, W2, b.Wth2, W3,
                                                       b.Wth3);
  if (combined) {
    const int M = 2 * kN;
    const int* ei0 = (const int*)d_in[1];
    const int* ei1 = (const int*)d_in[4];
    prep2<<<(2 * kN * 64 + 255) / 256, 256, 0, stream>>>(
        (const float*)d_in[0], (const float*)d_in[3], b.R1h, b.cnt, b.total);
    count_edges2<<<(2 * kE + 255) / 256, 256, 0, stream>>>(ei0 + kE, ei1 + kE,
                                                           b.cnt);
    alloc_ranges<<<(M + 255) / 256, 256, 0, stream>>>(b.cnt, b.start, b.cursor,
                                                      b.total, b.csr, M);
    fill_edges2<<<(2 * kE + 255) / 256, 256, 0, stream>>>(ei0, ei0 + kE, ei1,
                                                          ei1 + kE, b.cursor, b.csr);
    run_layers(b, d_in, M, stream);
    for (int enc = 0; enc < 2; ++enc) {
      const int* batch = (const int*)d_in[enc * 3 + 2];
      pool_max<<<kG, 128, 0, stream>>>(b.R1f + (size_t)enc * kN * 128, batch,
                                       b.emb + (size_t)enc * kG * 128, kN);
    }
  } else {
    for (int enc = 0; enc < 2; ++enc) {
      const float* x = (const float*)d_in[enc * 3 + 0];
      const int* ei = (const int*)d_in[enc * 3 + 1];
      const int* batch = (const int*)d_in[enc * 3 + 2];
      prep<<<(kN * 64 + 255) / 256, 256, 0, stream>>>(x, b.R1h, b.cnt, b.total,
                                                      kN * 64, kN);
      count_edges<<<(kE + 255) / 256, 256, 0, stream>>>(ei + kE, b.cnt, kE);
      alloc_ranges<<<(kN + 255) / 256, 256, 0, stream>>>(b.cnt, b.start, b.cursor,
                                                         b.total, b.csr, kN);
      fill_edges<<<(kE + 255) / 256, 256, 0, stream>>>(ei, ei + kE, b.cursor, b.csr,
                                                       kE);
      run_layers(b, d_in, kN, stream);
      pool_max<<<kG, 128, 0, stream>>>(b.R1f, batch, b.emb + (size_t)enc * kG * 128,
                                       kN);
    }
  }
  mlp_head<<<kG, 128, 0, stream>>>(b.emb, b.emb + (size_t)kG * 128, mw1, mb1, mw2,
                                   mb2, (float*)d_out);
}

// Round 2
// 695.518 us; speedup vs baseline: 1.0500x; 1.0121x over previous
//
#include <hip/hip_runtime.h>
#include <cstdint>

namespace {
constexpr int kN = 50000;          // nodes per encoder
constexpr int kE = 200000;         // directed edges per encoder (pre self-loop)
constexpr int kE2 = kE + kN;       // with self loops (per encoder)
constexpr int kG = 256;            // graphs per encoder
constexpr float kNegSlope = 0.2f;
}

using half8   = __attribute__((ext_vector_type(8))) _Float16;
using floatx4 = __attribute__((ext_vector_type(4))) float;

__device__ __forceinline__ void gld_lds16(const void* g, void* l) {
  __builtin_amdgcn_global_load_lds(
      (const __attribute__((address_space(1))) unsigned int*)g,
      (__attribute__((address_space(3))) unsigned int*)l, 16, 0, 0);
}

// fast exp: e^x = 2^(x*log2(e)) via hardware v_exp_f32 (no libm call)
__device__ __forceinline__ float fexp(float x) {
  return __builtin_amdgcn_exp2f(x * 1.44269504088896f);
}

// ---------------- fp16 MFMA GEMM: C[M,N] = A[M,K] @ B[K,N] -----------
// R14: 256xBN tile, 8 waves, BK=64, double-buffered LDS (2x64KB / 2x48KB).
// Rationale: R13 showed the 128^2 tile is STAGING-TRAFFIC bound, not
// vmcnt-drain bound (dbuf+counted vmcnt changed nothing; 822 MB of
// global->LDS traffic at 6.9 TB/s == the 119us). Quadrupling tile area
// halves staged bytes (A staged N/BN times, B staged M/BM times):
// l2: 822 -> 408 MB. LDS layout stays the conflict-free packed-subtile
// form [kh][rowgrp][q][r16][16B] (bank-conflict counter == 0) which also
// satisfies global_load_lds's linear-dest rule (base + lane*16).
// XCD swizzle: x=blockIdx&7 -> XCD; the CT col-tiles of a row-tile are
// adjacent blockIdx (differ by 8) -> same XCD, co-timed -> A staged from
// one L2 fill.
template <int OUTF16, int BN, int CT>
__global__ __launch_bounds__(512, 2) void gemm256(
    const _Float16* __restrict__ A, const _Float16* __restrict__ B,
    void* __restrict__ Cv, int M, int N, int K) {
  constexpr int ASLOTS = 2048;            // 256 rows * 64 k * 2B / 16
  constexpr int BSLOTS = BN * 8;          // BN rows * 64 k * 2B / 16
  constexpr int LPT = (ASLOTS + BSLOTS) / 512;   // loads/thread/stage: 8 or 6
  constexpr int BUFB = (ASLOTS + BSLOTS) * 16;   // 64KB or 48KB
  constexpr int WN = (BN == 256) ? 4 : 2;        // waves along N
  constexpr int WM = 8 / WN;                     // waves along M
  constexpr int WTM = 256 / WM;                  // 128 or 64
  constexpr int WTN = BN / WN;                   // 64
  constexpr int MI = WTM / 16;                   // 8 or 4
  constexpr int NI = WTN / 16;                   // 4
  __shared__ alignas(16) char smem[2 * BUFB];    // 128KB or 96KB
  const int t = threadIdx.x;
  const int w = t >> 6, l = t & 63;
  const int x = blockIdx.x & 7, s = blockIdx.x >> 3;
  const int col = (CT == 1) ? 0 : (s & (CT - 1));
  const int rt = ((CT == 1) ? s : (s >> 1)) * 8 + x;
  const int bm = rt * 256;
  const int bn = col * BN;
  if (bm >= M) return;  // padded row-tiles: whole block exits (no barrier)
  const int wr = w / WN, wc = w % WN;
  const int quad = l >> 4, lrow = l & 15;

  floatx4 acc[MI][NI];
#pragma unroll
  for (int mi = 0; mi < MI; ++mi)
#pragma unroll
    for (int ni = 0; ni < NI; ++ni) acc[mi][ni] = (floatx4){0.f, 0.f, 0.f, 0.f};

  // stage one 256x64 A-tile + BNx64 B-tile (LPT gld_lds16 per thread)
  auto stage = [&](char* buf, int k0) {
#pragma unroll
    for (int i = 0; i < ASLOTS / 512; ++i) {  // 4
      const int sl = i * 512 + t;
      const int kh = sl >> 10;                // 1024 slots per kh block
      const int r = sl & 1023;
      const int row = ((r >> 6) << 4) + (r & 15);
      const int q = (r >> 4) & 3;
      int ga = bm + row;
      ga = (ga < M) ? ga : (M - 1);           // clamp: keep lanes active
      gld_lds16(A + (size_t)ga * K + k0 + kh * 32 + q * 8, buf + sl * 16);
    }
#pragma unroll
    for (int i = 0; i < BSLOTS / 512; ++i) {  // 4 or 2
      const int sl = i * 512 + t;
      const int kh = sl / (BSLOTS / 2);
      const int r = sl % (BSLOTS / 2);
      const int row = ((r >> 6) << 4) + (r & 15);
      const int q = (r >> 4) & 3;
      gld_lds16(B + (size_t)(bn + row) * K + k0 + kh * 32 + q * 8,
                buf + (ASLOTS + sl) * 16);
    }
  };

  stage(smem, 0);  // prologue: LPT loads in flight
  int cur = 0;
  for (int k0 = 0; k0 < K; k0 += 64) {
    char* bufc = smem + cur * BUFB;
    if (k0 + 64 < K) {
      stage(smem + (cur ^ 1) * BUFB, k0 + 64);  // 2*LPT in flight
      if constexpr (LPT == 8)
        asm volatile("s_waitcnt vmcnt(8)" ::: "memory");  // cur's 8 landed
      else
        asm volatile("s_waitcnt vmcnt(6)" ::: "memory");
    } else {
      asm volatile("s_waitcnt vmcnt(0)" ::: "memory");    // last tile: drain
    }
    __builtin_amdgcn_s_barrier();        // all waves: buf[cur] ready
    asm volatile("" ::: "memory");
#pragma unroll
    for (int kh = 0; kh < 2; ++kh) {
      half8 fa[MI], fb[NI];
#pragma unroll
      for (int mi = 0; mi < MI; ++mi)
        fa[mi] = *(const half8*)(bufc + ((kh * 16 + wr * MI + mi) << 10) + l * 16);
#pragma unroll
      for (int ni = 0; ni < NI; ++ni)
        fb[ni] = *(const half8*)(bufc + ASLOTS * 16 +
                                 ((kh * (BN / 16) + wc * NI + ni) << 10) + l * 16);
      __builtin_amdgcn_s_setprio(1);
#pragma unroll
      for (int mi = 0; mi < MI; ++mi)
#pragma unroll
        for (int ni = 0; ni < NI; ++ni)
          acc[mi][ni] = __builtin_amdgcn_mfma_f32_16x16x32_f16(
              fa[mi], fb[ni], acc[mi][ni], 0, 0, 0);
      __builtin_amdgcn_s_setprio(0);
    }
    asm volatile("" ::: "memory");
    __builtin_amdgcn_s_barrier();        // buf[cur] free for re-staging
    cur ^= 1;
  }
  // epilogue: C/D layout col=lane&15, row=quad*4+reg
  const int colbase = bn + wc * WTN + lrow;
#pragma unroll
  for (int mi = 0; mi < MI; ++mi) {
    const int rbase = bm + wr * WTM + mi * 16 + quad * 4;
#pragma unroll
    for (int r = 0; r < 4; ++r) {
      const int grow = rbase + r;
      if (grow < M) {
        if constexpr (OUTF16) {
          _Float16* C = (_Float16*)Cv;
#pragma unroll
          for (int ni = 0; ni < NI; ++ni)
            C[(size_t)grow * N + colbase + ni * 16] = (_Float16)acc[mi][ni][r];
        } else {
          float* C = (float*)Cv;
#pragma unroll
          for (int ni = 0; ni < NI; ++ni)
            C[(size_t)grow * N + colbase + ni * 16] = acc[mi][ni][r];
        }
      }
    }
  }
}

// ------- all three weight transposes + f16 casts in one kernel --------
__global__ void wt_split_all(const float* __restrict__ W1, _Float16* Th1,
                             const float* __restrict__ W2, _Float16* Th2,
                             const float* __restrict__ W3, _Float16* Th3) {
  int idx = blockIdx.x * blockDim.x + threadIdx.x;
  const float* W;
  _Float16* Th;
  int K, N;
  if (idx < 64 * 512) {
    W = W1; Th = Th1; K = 64; N = 512;
  } else if (idx < 64 * 512 + 512 * 512) {
    idx -= 64 * 512;
    W = W2; Th = Th2; K = 512; N = 512;
  } else if (idx < 64 * 512 + 512 * 512 + 512 * 128) {
    idx -= 64 * 512 + 512 * 512;
    W = W3; Th = Th3; K = 512; N = 128;
  } else {
    return;
  }
  const int k = idx / N;
  const int n = idx - k * N;
  Th[n * K + k] = (_Float16)W[idx];
}

// ------- combined prep: both x casts + cnt=1 (2N) + total=0 -----------
__global__ void prep2(const float* __restrict__ x0, const float* __restrict__ x1,
                      _Float16* __restrict__ Xh, int* __restrict__ cnt,
                      int* __restrict__ total) {
  const int idx = blockIdx.x * blockDim.x + threadIdx.x;
  const int half = kN * 64;
  if (idx < half) Xh[idx] = (_Float16)x0[idx];
  else if (idx < 2 * half) Xh[idx] = (_Float16)x1[idx - half];
  if (idx < 2 * kN) cnt[idx] = 1;  // the self loop
  if (idx == 0) *total = 0;
}
// ------- single-encoder prep (fallback path) --------------------------
__global__ void prep(const float* __restrict__ X, _Float16* __restrict__ Xh,
                     int* __restrict__ cnt, int* __restrict__ total, int nsplit,
                     int n) {
  const int idx = blockIdx.x * blockDim.x + threadIdx.x;
  if (idx < nsplit) Xh[idx] = (_Float16)X[idx];
  if (idx < n) cnt[idx] = 1;
  if (idx == 0) *total = 0;
}

// ---------------- CSR (by dst) build ----------------------------------
__global__ void count_edges2(const int* __restrict__ d0, const int* __restrict__ d1,
                             int* __restrict__ cnt) {
  const int i = blockIdx.x * blockDim.x + threadIdx.x;
  if (i < kE) atomicAdd(&cnt[d0[i]], 1);
  else if (i < 2 * kE) atomicAdd(&cnt[d1[i - kE] + kN], 1);
}
__global__ void fill_edges2(const int* __restrict__ s0, const int* __restrict__ d0,
                            const int* __restrict__ s1, const int* __restrict__ d1,
                            int* __restrict__ cursor, int* __restrict__ csr) {
  const int i = blockIdx.x * blockDim.x + threadIdx.x;
  if (i < kE) {
    const int p = atomicAdd(&cursor[d0[i]], 1);
    csr[p] = s0[i];
  } else if (i < 2 * kE) {
    const int j = i - kE;
    const int p = atomicAdd(&cursor[d1[j] + kN], 1);
    csr[p] = s1[j] + kN;
  }
}
__global__ void count_edges(const int* __restrict__ dst, int* __restrict__ cnt,
                            int ne) {
  const int i = blockIdx.x * blockDim.x + threadIdx.x;
  if (i < ne) atomicAdd(&cnt[dst[i]], 1);
}
__global__ void fill_edges(const int* __restrict__ src, const int* __restrict__ dst,
                           int* __restrict__ cursor, int* __restrict__ csr, int ne) {
  const int i = blockIdx.x * blockDim.x + threadIdx.x;
  if (i < ne) {
    const int p = atomicAdd(&cursor[dst[i]], 1);
    csr[p] = src[i];
  }
}
__global__ void alloc_ranges(const int* __restrict__ cnt, int* __restrict__ start,
                             int* __restrict__ cursor, int* __restrict__ total,
                             int* __restrict__ csr, int n) {
  const int i = blockIdx.x * blockDim.x + threadIdx.x;
  const int lane = threadIdx.x & 63;
  const int v = (i < n) ? cnt[i] : 0;
  int sc = v;
#pragma unroll
  for (int off = 1; off < 64; off <<= 1) {
    const int t = __shfl_up(sc, off);
    if (lane >= off) sc += t;
  }
  const int wtot = __shfl(sc, 63);
  int base = 0;
  if (lane == 63) base = atomicAdd(total, wtot);
  base = __shfl(base, 63);
  const int st = base + sc - v;
  if (i < n) {
    start[i] = st;
    cursor[i] = st + 1;
    csr[st] = i;  // self loop first
  }
}

// ---------------- GAT aggregate, layers 1-2 (f16 h) -------------------
// Attention dots fused in: <h[src],a_src> from the gathered fragment
// (8 FMA + 4 shfl_xor in the 16-lane head group); <h[node],a_dst> from
// the self-loop gather (CSR entry 0).
__global__ void gat_agg4(const _Float16* __restrict__ h,
                         const float* __restrict__ a_src,
                         const float* __restrict__ a_dst,
                         const int* __restrict__ start, const int* __restrict__ cnt,
                         const int* __restrict__ csr_src,
                         const float* __restrict__ bias,
                         _Float16* __restrict__ outH, int n_nodes) {
  const int gtid = blockIdx.x * blockDim.x + threadIdx.x;
  const int node = gtid >> 6;
  const int lane = threadIdx.x & 63;
  if (node >= n_nodes) return;
  const int ch = lane * 8;
  float as_r[8], ad_r[8];
#pragma unroll
  for (int j = 0; j < 8; ++j) {
    as_r[j] = a_src[ch + j];
    ad_r[j] = a_dst[ch + j];
  }
  const int s = start[node];
  const int c = cnt[node];
  // self loop first (csr_src[s] == node): gives both dst-dot and its edge
  const half8 vs = *(const half8*)(h + (size_t)node * 512 + ch);
  float fs[8];
  float t_src = 0.f, t_dst = 0.f;
#pragma unroll
  for (int j = 0; j < 8; ++j) {
    fs[j] = (float)vs[j];
    t_src = fmaf(fs[j], as_r[j], t_src);
    t_dst = fmaf(fs[j], ad_r[j], t_dst);
  }
#pragma unroll
  for (int off = 1; off < 16; off <<= 1) {
    t_src += __shfl_xor(t_src, off);
    t_dst += __shfl_xor(t_dst, off);
  }
  const float ad = t_dst;  // <h[node], a_dst> for this head
  float es = t_src + ad;
  es = (es > 0.f) ? es : kNegSlope * es;
  const float ws = fexp(es);
  float d0 = ws, d1 = 0.f;
  float a0[8], a1[8];
#pragma unroll
  for (int j = 0; j < 8; ++j) {
    a0[j] = ws * fs[j];
    a1[j] = 0.f;
  }
  int i = 1;
  for (; i + 2 <= c; i += 2) {
    const int s0 = csr_src[s + i];
    const int s1 = csr_src[s + i + 1];
    const half8 v0 = *(const half8*)(h + (size_t)s0 * 512 + ch);
    const half8 v1 = *(const half8*)(h + (size_t)s1 * 512 + ch);
    float f0[8], f1[8];
    float t0 = 0.f, t1 = 0.f;
#pragma unroll
    for (int j = 0; j < 8; ++j) {
      f0[j] = (float)v0[j];
      f1[j] = (float)v1[j];
      t0 = fmaf(f0[j], as_r[j], t0);
      t1 = fmaf(f1[j], as_r[j], t1);
    }
#pragma unroll
    for (int off = 1; off < 16; off <<= 1) {
      t0 += __shfl_xor(t0, off);
      t1 += __shfl_xor(t1, off);
    }
    float e0 = t0 + ad;
    float e1 = t1 + ad;
    e0 = (e0 > 0.f) ? e0 : kNegSlope * e0;
    e1 = (e1 > 0.f) ? e1 : kNegSlope * e1;
    const float w0 = fexp(e0);
    const float w1 = fexp(e1);
    d0 += w0;
    d1 += w1;
#pragma unroll
    for (int j = 0; j < 8; ++j) {
      a0[j] = fmaf(w0, f0[j], a0[j]);
      a1[j] = fmaf(w1, f1[j], a1[j]);
    }
  }
  if (i < c) {
    const int s0 = csr_src[s + i];
    const half8 v0 = *(const half8*)(h + (size_t)s0 * 512 + ch);
    float f0[8];
    float t0 = 0.f;
#pragma unroll
    for (int j = 0; j < 8; ++j) {
      f0[j] = (float)v0[j];
      t0 = fmaf(f0[j], as_r[j], t0);
    }
#pragma unroll
    for (int off = 1; off < 16; off <<= 1) t0 += __shfl_xor(t0, off);
    float e0 = t0 + ad;
    e0 = (e0 > 0.f) ? e0 : kNegSlope * e0;
    const float w0 = fexp(e0);
    d0 += w0;
#pragma unroll
    for (int j = 0; j < 8; ++j) a0[j] = fmaf(w0, f0[j], a0[j]);
  }
  const float inv = 1.f / (d0 + d1 + 1e-16f);
  half8 H;
#pragma unroll
  for (int j = 0; j < 8; ++j) {
    float v = (a0[j] + a1[j]) * inv + bias[ch + j];
    v = (v > 0.f) ? v : (fexp(v) - 1.f);  // elu via hw exp
    H[j] = (_Float16)v;
  }
  *(half8*)(outH + (size_t)node * 512 + ch) = H;
}

// ---------- GAT aggregate, layer 3 (H=1, fp32, fused dots) ------------
__global__ void gat_agg_l3(const float* __restrict__ h,
                           const float* __restrict__ a_src,
                           const float* __restrict__ a_dst,
                           const int* __restrict__ start, const int* __restrict__ cnt,
                           const int* __restrict__ csr_src,
                           const float* __restrict__ bias,
                           float* __restrict__ out, int n_nodes) {
  const int gtid = blockIdx.x * blockDim.x + threadIdx.x;
  const int node = gtid >> 6;
  const int lane = threadIdx.x & 63;
  if (node >= n_nodes) return;
  const float2 asv = *(const float2*)(a_src + lane * 2);
  const float2 adv = *(const float2*)(a_dst + lane * 2);
  const int s = start[node];
  const int c = cnt[node];
  // self loop first: dst-dot + its own edge
  const float2 vs = *(const float2*)(h + (size_t)node * 128 + lane * 2);
  float t_src = fmaf(vs.x, asv.x, vs.y * asv.y);
  float t_dst = fmaf(vs.x, adv.x, vs.y * adv.y);
#pragma unroll
  for (int off = 1; off < 64; off <<= 1) {
    t_src += __shfl_xor(t_src, off);
    t_dst += __shfl_xor(t_dst, off);
  }
  const float ad = t_dst;
  float es = t_src + ad;
  es = (es > 0.f) ? es : kNegSlope * es;
  const float ws = fexp(es);
  float2 a0 = make_float2(ws * vs.x, ws * vs.y);
  float2 a1 = make_float2(0.f, 0.f);
  float d0 = ws, d1 = 0.f;
  int i = 1;
  for (; i + 2 <= c; i += 2) {
    const int s0 = csr_src[s + i];
    const int s1 = csr_src[s + i + 1];
    const float2 v0 = *(const float2*)(h + (size_t)s0 * 128 + lane * 2);
    const float2 v1 = *(const float2*)(h + (size_t)s1 * 128 + lane * 2);
    float t0 = fmaf(v0.x, asv.x, v0.y * asv.y);
    float t1 = fmaf(v1.x, asv.x, v1.y * asv.y);
#pragma unroll
    for (int off = 1; off < 64; off <<= 1) {
      t0 += __shfl_xor(t0, off);
      t1 += __shfl_xor(t1, off);
    }
    float e0 = t0 + ad;
    float e1 = t1 + ad;
    e0 = (e0 > 0.f) ? e0 : kNegSlope * e0;
    e1 = (e1 > 0.f) ? e1 : kNegSlope * e1;
    const float w0 = fexp(e0);
    const float w1 = fexp(e1);
    d0 += w0;
    d1 += w1;
    a0.x = fmaf(w0, v0.x, a0.x); a1.x = fmaf(w1, v1.x, a1.x);
    a0.y = fmaf(w0, v0.y, a0.y); a1.y = fmaf(w1, v1.y, a1.y);
  }
  if (i < c) {
    const int s0 = csr_src[s + i];
    const float2 v0 = *(const float2*)(h + (size_t)s0 * 128 + lane * 2);
    float t0 = fmaf(v0.x, asv.x, v0.y * asv.y);
#pragma unroll
    for (int off = 1; off < 64; off <<= 1) t0 += __shfl_xor(t0, off);
    float e0 = t0 + ad;
    e0 = (e0 > 0.f) ? e0 : kNegSlope * e0;
    const float w0 = fexp(e0);
    d0 += w0;
    a0.x = fmaf(w0, v0.x, a0.x);
    a0.y = fmaf(w0, v0.y, a0.y);
  }
  const float inv = 1.f / (d0 + d1 + 1e-16f);
  *(float2*)(out + (size_t)node * 128 + lane * 2) =
      make_float2((a0.x + a1.x) * inv + bias[lane * 2],
                  (a0.y + a1.y) * inv + bias[lane * 2 + 1]);
}

// ---------------- global max pool over sorted batch -------------------
__global__ void pool_max(const float* __restrict__ x, const int* __restrict__ batch,
                         float* __restrict__ emb, int n_nodes) {
  __shared__ int lohi[2];
  const int g = blockIdx.x;
  if (threadIdx.x == 0) {
    int lo = 0, hi = n_nodes;
    while (lo < hi) {
      const int mid = (lo + hi) >> 1;
      if (batch[mid] < g) lo = mid + 1; else hi = mid;
    }
    lohi[0] = lo;
    hi = n_nodes;
    while (lo < hi) {
      const int mid = (lo + hi) >> 1;
      if (batch[mid] < g + 1) lo = mid + 1; else hi = mid;
    }
    lohi[1] = lo;
  }
  __syncthreads();
  const int lo = lohi[0], hi = lohi[1];
  const int c = threadIdx.x;  // 128 channels
  float m = -1e30f;
  for (int nid = lo; nid < hi; ++nid) m = fmaxf(m, x[(size_t)nid * 128 + c]);
  emb[g * 128 + c] = (lo < hi) ? m : 0.f;
}

// ---------------- final MLP head --------------------------------------
__global__ void mlp_head(const float* __restrict__ e1, const float* __restrict__ e2,
                         const float* __restrict__ mw1, const float* __restrict__ mb1,
                         const float* __restrict__ mw2, const float* __restrict__ mb2,
                         float* __restrict__ out) {
  __shared__ float z[256];
  __shared__ float red[128];
  const int g = blockIdx.x;
  const int j = threadIdx.x;  // 128
  z[j] = e1[g * 128 + j];
  z[j + 128] = e2[g * 128 + j];
  __syncthreads();
  float acc = mb1[j];
  for (int k = 0; k < 256; ++k) acc = fmaf(z[k], mw1[k * 128 + j], acc);
  acc = fmaxf(acc, 0.f) * mw2[j];
  red[j] = acc;
  __syncthreads();
  for (int s = 64; s > 0; s >>= 1) {
    if (j < s) red[j] += red[j + s];
    __syncthreads();
  }
  if (j == 0) out[g] = red[0] + mb2[0];
}

// ---------------- launcher --------------------------------------------
namespace {
struct Bufs {
  _Float16 *R1h, *R2h;
  float *R1f, *R2f, *asrc, *adst;
  int *cnt, *start, *cursor, *csr, *total;
  _Float16 *Wth1, *Wth2, *Wth3;
  float* emb;
  size_t need;
};

Bufs plan(void* d_ws, int M, int E) {
  Bufs b;
  char* w = (char*)d_ws;
  size_t off = 0;
  auto take = [&](size_t bytes) -> void* {
    void* p = w + off;
    off += (bytes + 255) & ~(size_t)255;
    return p;
  };
  b.R1h = (_Float16*)take((size_t)M * 512 * 2);  // f16 activations
  b.R1f = (float*)b.R1h;                         // layer-3 out alias [M,128]
  b.R2h = (_Float16*)take((size_t)M * 512 * 2);  // h f16; l3 fp32 alias
  b.R2f = (float*)b.R2h;
  b.asrc = (float*)take((size_t)M * 4 * 4);      // (unused since fusion)
  b.adst = (float*)take((size_t)M * 4 * 4);
  b.cnt = (int*)take((size_t)M * 4);
  b.start = (int*)take((size_t)M * 4);
  b.cursor = (int*)take((size_t)M * 4);
  b.csr = (int*)take((size_t)E * 4);
  b.total = (int*)take(256);
  b.Wth1 = (_Float16*)take((size_t)64 * 512 * 2);
  b.Wth2 = (_Float16*)take((size_t)512 * 512 * 2);
  b.Wth3 = (_Float16*)take((size_t)512 * 128 * 2);
  b.emb = (float*)take((size_t)2 * kG * 128 * 4);
  b.need = off;
  return b;
}

void run_layers(const Bufs& b, void* const* d_in, int M, hipStream_t stream) {
  const float* as1 = (const float*)d_in[7];
  const float* ad1 = (const float*)d_in[8];
  const float* b1 = (const float*)d_in[9];
  const float* as2 = (const float*)d_in[11];
  const float* ad2 = (const float*)d_in[12];
  const float* b2 = (const float*)d_in[13];
  const float* as3 = (const float*)d_in[15];
  const float* ad3 = (const float*)d_in[16];
  const float* b3 = (const float*)d_in[17];
  const int nodeBlocks = (M * 64) / 256;  // 1 wave/node
  const int MT = (M + 255) / 256;         // 256-row tiles
  const int SP = (MT + 7) / 8;            // row-tile groups of 8 (XCD map)

  // layer 1: [M,64] @ [64,512], h -> f16 (A1h aliases R1h)
  gemm256<1, 256, 2><<<SP * 16, 512, 0, stream>>>(b.R1h, b.Wth1, b.R2h, M, 512, 64);
  gat_agg4<<<nodeBlocks, 256, 0, stream>>>(b.R2h, as1, ad1, b.start, b.cnt,
                                           b.csr, b1, b.R1h, M);
  // layer 2: [M,512] @ [512,512], h -> f16
  gemm256<1, 256, 2><<<SP * 16, 512, 0, stream>>>(b.R1h, b.Wth2, b.R2h, M, 512, 512);
  gat_agg4<<<nodeBlocks, 256, 0, stream>>>(b.R2h, as2, ad2, b.start, b.cnt,
                                           b.csr, b2, b.R1h, M);
  // layer 3: [M,512] @ [512,128], H=1, no elu, fp32 out
  gemm256<0, 128, 1><<<SP * 8, 512, 0, stream>>>(b.R1h, b.Wth3, b.R2f, M, 128, 512);
  gat_agg_l3<<<nodeBlocks, 256, 0, stream>>>(b.R2f, as3, ad3, b.start, b.cnt,
                                             b.csr, b3, b.R1f, M);
}
}  // namespace

extern "C" void kernel_launch(void* const* d_in, const int* in_sizes, int n_in,
                              void* d_out, int out_size, void* d_ws, size_t ws_size,
                              hipStream_t stream) {
  (void)in_sizes; (void)n_in; (void)out_size;
  const float* W1 = (const float*)d_in[6];
  const float* W2 = (const float*)d_in[10];
  const float* W3 = (const float*)d_in[14];
  const float* mw1 = (const float*)d_in[18];
  const float* mb1 = (const float*)d_in[19];
  const float* mw2 = (const float*)d_in[20];
  const float* mb2 = (const float*)d_in[21];

  // Prefer combined (both encoders batched, M=2N) if it fits the workspace.
  Bufs bc = plan(d_ws, 2 * kN, 2 * kE2);
  const bool combined = bc.need <= ws_size;
  Bufs b = combined ? bc : plan(d_ws, kN, kE2);

  const int wtot = 64 * 512 + 512 * 512 + 512 * 128;
  wt_split_all<<<(wtot + 255) / 256, 256, 0, stream>>>(W1, b.Wth1, W2, b.Wth2, W3,
                                                       b.Wth3);
  if (combined) {
    const int M = 2 * kN;
    const int* ei0 = (const int*)d_in[1];
    const int* ei1 = (const int*)d_in[4];
    prep2<<<(2 * kN * 64 + 255) / 256, 256, 0, stream>>>(
        (const float*)d_in[0], (const float*)d_in[3], b.R1h, b.cnt, b.total);
    count_edges2<<<(2 * kE + 255) / 256, 256, 0, stream>>>(ei0 + kE, ei1 + kE,
                                                           b.cnt);
    alloc_ranges<<<(M + 255) / 256, 256, 0, stream>>>(b.cnt, b.start, b.cursor,
                                                      b.total, b.csr, M);
    fill_edges2<<<(2 * kE + 255) / 256, 256, 0, stream>>>(ei0, ei0 + kE, ei1,
                                                          ei1 + kE, b.cursor, b.csr);
    run_layers(b, d_in, M, stream);
    for (int enc = 0; enc < 2; ++enc) {
      const int* batch = (const int*)d_in[enc * 3 + 2];
      pool_max<<<kG, 128, 0, stream>>>(b.R1f + (size_t)enc * kN * 128, batch,
                                       b.emb + (size_t)enc * kG * 128, kN);
    }
  } else {
    for (int enc = 0; enc < 2; ++enc) {
      const float* x = (const float*)d_in[enc * 3 + 0];
      const int* ei = (const int*)d_in[enc * 3 + 1];
      const int* batch = (const int*)d_in[enc * 3 + 2];
      prep<<<(kN * 64 + 255) / 256, 256, 0, stream>>>(x, b.R1h, b.cnt, b.total,
                                                      kN * 64, kN);
      count_edges<<<(kE + 255) / 256, 256, 0, stream>>>(ei + kE, b.cnt, kE);
      alloc_ranges<<<(kN + 255) / 256, 256, 0, stream>>>(b.cnt, b.start, b.cursor,
                                                         b.total, b.csr, kN);
      fill_edges<<<(kE + 255) / 256, 256, 0, stream>>>(ei, ei + kE, b.cursor, b.csr,
                                                       kE);
      run_layers(b, d_in, kN, stream);
      pool_max<<<kG, 128, 0, stream>>>(b.R1f, batch, b.emb + (size_t)enc * kG * 128,
                                       kN);
    }
  }
  mlp_head<<<kG, 128, 0, stream>>>(b.emb, b.emb + (size_t)kG * 128, mw1, mb1, mw2,
                                   mb2, (float*)d_out);
}

// Round 3
// 671.948 us; speedup vs baseline: 1.0868x; 1.0351x over previous
//
#include <hip/hip_runtime.h>
#include <cstdint>

namespace {
constexpr int kN = 50000;          // nodes per encoder
constexpr int kE = 200000;         // directed edges per encoder (pre self-loop)
constexpr int kE2 = kE + kN;       // with self loops (per encoder)
constexpr int kG = 256;            // graphs per encoder
constexpr float kNegSlope = 0.2f;
}

using half8   = __attribute__((ext_vector_type(8))) _Float16;
using floatx4 = __attribute__((ext_vector_type(4))) float;

__device__ __forceinline__ void gld_lds16(const void* g, void* l) {
  __builtin_amdgcn_global_load_lds(
      (const __attribute__((address_space(1))) unsigned int*)g,
      (__attribute__((address_space(3))) unsigned int*)l, 16, 0, 0);
}

// fast exp: e^x = 2^(x*log2(e)) via hardware v_exp_f32 (no libm call)
__device__ __forceinline__ float fexp(float x) {
  return __builtin_amdgcn_exp2f(x * 1.44269504088896f);
}

// ---------------- fp16 MFMA GEMM: C[M,N] = A[M,K] @ B[K,N] -----------
// R15: deep-pipelined ring schedule (T3+T4+T5). R13 (dbuf dist-1) and
// R14 (256^2 tile) both landed at the 2-phase structural ceiling
// (~440 TF, MfmaUtil 19%) — m233's measured 72% stage+vmcnt+barrier
// overhead. Fix: 4-slot LDS ring (BK=32, 32KB/slot), prefetch distance
// 3: tile kt+3's loads issue in 2 chunks interleaved between the two
// 16-MFMA half-phases of tile kt; the pre-compute s_waitcnt vmcnt(10)
// targets loads issued 3 tiles (~7.5K cyc) earlier => no stall.
// Counted waits never reach 0 in the loop (m218: counted-vs-drain is
// the entire pipelining gain). setprio(1) around MFMA clusters (T5 —
// pays once the schedule has wave role diversity). LDS layout is the
// proven packed conflict-free subtile form (bank conflicts == 0), also
// satisfying global_load_lds's linear-dest rule.
// Beyond-NT prefetches are issued with k0 clamped (garbage into a dead
// slot; keeps the vmcnt literals valid for any NT) and drained by the
// final vmcnt(0) before the epilogue so no LDS write outlives the block.
template <int OUTF16, int BN, int CT>
__global__ __launch_bounds__(512, 2) void gemm_ring(
    const _Float16* __restrict__ A, const _Float16* __restrict__ B,
    void* __restrict__ Cv, int M, int N, int K) {
  constexpr int ASL = 1024;                // A slots/tile (256 rows x 32k x 2B /16)
  constexpr int BSL = BN * 4;              // B slots/tile (1024 or 512)
  constexpr int SLOT = (ASL + BSL) * 16;   // 32KB or 24KB
  constexpr int LPT = (ASL + BSL) / 512;   // loads/thread/tile: 4 or 3
  constexpr int WN = (BN == 256) ? 4 : 2;  // waves along N
  constexpr int WM = 8 / WN;
  constexpr int WTM = 256 / WM;            // 128 or 64
  constexpr int WTN = BN / WN;             // 64
  constexpr int MI = WTM / 16;             // 8 or 4
  constexpr int NI = WTN / 16;             // 4
  __shared__ alignas(16) char smem[4 * SLOT];  // 128KB or 96KB ring
  const int t = threadIdx.x;
  const int w = t >> 6, l = t & 63;
  const int x = blockIdx.x & 7, s = blockIdx.x >> 3;
  const int col = (CT == 1) ? 0 : (s & (CT - 1));
  const int rt = ((CT == 1) ? s : (s >> 1)) * 8 + x;
  const int bm = rt * 256;
  const int bn = col * BN;
  if (bm >= M) return;  // padded row-tiles: whole block exits (no barrier)
  const int wr = w / WN, wc = w % WN;
  const int quad = l >> 4, lrow = l & 15;

  floatx4 acc[MI][NI];
#pragma unroll
  for (int mi = 0; mi < MI; ++mi)
#pragma unroll
    for (int ni = 0; ni < NI; ++ni) acc[mi][ni] = (floatx4){0.f, 0.f, 0.f, 0.f};

  // stage tile kt's A-part (2 loads) / B-part (LPT-2 loads) into ring slot
  auto stageA = [&](int kt) {
    char* buf = smem + (size_t)(kt & 3) * SLOT;
    int k0 = kt * 32;
    k0 = (k0 > K - 32) ? (K - 32) : k0;  // clamp: beyond-NT garbage stays in-bounds
#pragma unroll
    for (int i = 0; i < 2; ++i) {
      const int sl = i * 512 + t;
      const int row = ((sl >> 6) << 4) + (sl & 15);
      const int q = (sl >> 4) & 3;
      int ga = bm + row;
      ga = (ga < M) ? ga : (M - 1);      // clamp: keep lanes active
      gld_lds16(A + (size_t)ga * K + k0 + q * 8, buf + sl * 16);
    }
  };
  auto stageB = [&](int kt) {
    char* buf = smem + (size_t)(kt & 3) * SLOT + ASL * 16;
    int k0 = kt * 32;
    k0 = (k0 > K - 32) ? (K - 32) : k0;
#pragma unroll
    for (int i = 0; i < LPT - 2; ++i) {
      const int sl = i * 512 + t;
      const int row = ((sl >> 6) << 4) + (sl & 15);
      const int q = (sl >> 4) & 3;
      gld_lds16(B + (size_t)(bn + row) * K + k0 + q * 8, buf + sl * 16);
    }
  };

  // prologue: tiles 0,1,2 in flight (3*LPT loads)
  stageA(0); stageB(0);
  stageA(1); stageB(1);
  stageA(2); stageB(2);

  const int NT = K >> 5;
  for (int kt = 0; kt < NT; ++kt) {
    char* bufc = smem + (size_t)(kt & 3) * SLOT;
    // ---- phase A ----
    stageA(kt + 3);  // 2 loads of tile kt+3 (slot of finished tile kt-1)
    if constexpr (BN == 256)
      asm volatile("s_waitcnt vmcnt(10)" ::: "memory");  // tile kt's 4 landed
    else
      asm volatile("s_waitcnt vmcnt(8)" ::: "memory");   // tile kt's 3 landed
    __builtin_amdgcn_s_barrier();        // all waves: slot[kt&3] ready
    asm volatile("" ::: "memory");
    half8 fa[MI], fb[NI];
#pragma unroll
    for (int ni = 0; ni < NI; ++ni)
      fb[ni] = *(const half8*)(bufc + ASL * 16 + ((wc * NI + ni) << 10) + l * 16);
#pragma unroll
    for (int mi = 0; mi < MI / 2; ++mi)
      fa[mi] = *(const half8*)(bufc + ((wr * MI + mi) << 10) + l * 16);
    __builtin_amdgcn_s_setprio(1);
#pragma unroll
    for (int mi = 0; mi < MI / 2; ++mi)
#pragma unroll
      for (int ni = 0; ni < NI; ++ni)
        acc[mi][ni] = __builtin_amdgcn_mfma_f32_16x16x32_f16(
            fa[mi], fb[ni], acc[mi][ni], 0, 0, 0);
    __builtin_amdgcn_s_setprio(0);
    // ---- phase B ----
    stageB(kt + 3);  // remaining loads of tile kt+3
#pragma unroll
    for (int mi = MI / 2; mi < MI; ++mi)
      fa[mi] = *(const half8*)(bufc + ((wr * MI + mi) << 10) + l * 16);
    __builtin_amdgcn_s_setprio(1);
#pragma unroll
    for (int mi = MI / 2; mi < MI; ++mi)
#pragma unroll
      for (int ni = 0; ni < NI; ++ni)
        acc[mi][ni] = __builtin_amdgcn_mfma_f32_16x16x32_f16(
            fa[mi], fb[ni], acc[mi][ni], 0, 0, 0);
    __builtin_amdgcn_s_setprio(0);
    asm volatile("" ::: "memory");
    __builtin_amdgcn_s_barrier();        // slot[kt&3] reusable for kt+4
  }
  asm volatile("s_waitcnt vmcnt(0)" ::: "memory");  // drain garbage prefetches
  // epilogue: C/D layout col=lane&15, row=quad*4+reg
  const int colbase = bn + wc * WTN + lrow;
#pragma unroll
  for (int mi = 0; mi < MI; ++mi) {
    const int rbase = bm + wr * WTM + mi * 16 + quad * 4;
#pragma unroll
    for (int r = 0; r < 4; ++r) {
      const int grow = rbase + r;
      if (grow < M) {
        if constexpr (OUTF16) {
          _Float16* C = (_Float16*)Cv;
#pragma unroll
          for (int ni = 0; ni < NI; ++ni)
            C[(size_t)grow * N + colbase + ni * 16] = (_Float16)acc[mi][ni][r];
        } else {
          float* C = (float*)Cv;
#pragma unroll
          for (int ni = 0; ni < NI; ++ni)
            C[(size_t)grow * N + colbase + ni * 16] = acc[mi][ni][r];
        }
      }
    }
  }
}

// ------- all three weight transposes + f16 casts in one kernel --------
__global__ void wt_split_all(const float* __restrict__ W1, _Float16* Th1,
                             const float* __restrict__ W2, _Float16* Th2,
                             const float* __restrict__ W3, _Float16* Th3) {
  int idx = blockIdx.x * blockDim.x + threadIdx.x;
  const float* W;
  _Float16* Th;
  int K, N;
  if (idx < 64 * 512) {
    W = W1; Th = Th1; K = 64; N = 512;
  } else if (idx < 64 * 512 + 512 * 512) {
    idx -= 64 * 512;
    W = W2; Th = Th2; K = 512; N = 512;
  } else if (idx < 64 * 512 + 512 * 512 + 512 * 128) {
    idx -= 64 * 512 + 512 * 512;
    W = W3; Th = Th3; K = 512; N = 128;
  } else {
    return;
  }
  const int k = idx / N;
  const int n = idx - k * N;
  Th[n * K + k] = (_Float16)W[idx];
}

// ------- combined prep: both x casts + cnt=1 (2N) + total=0 -----------
__global__ void prep2(const float* __restrict__ x0, const float* __restrict__ x1,
                      _Float16* __restrict__ Xh, int* __restrict__ cnt,
                      int* __restrict__ total) {
  const int idx = blockIdx.x * blockDim.x + threadIdx.x;
  const int half = kN * 64;
  if (idx < half) Xh[idx] = (_Float16)x0[idx];
  else if (idx < 2 * half) Xh[idx] = (_Float16)x1[idx - half];
  if (idx < 2 * kN) cnt[idx] = 1;  // the self loop
  if (idx == 0) *total = 0;
}
// ------- single-encoder prep (fallback path) --------------------------
__global__ void prep(const float* __restrict__ X, _Float16* __restrict__ Xh,
                     int* __restrict__ cnt, int* __restrict__ total, int nsplit,
                     int n) {
  const int idx = blockIdx.x * blockDim.x + threadIdx.x;
  if (idx < nsplit) Xh[idx] = (_Float16)X[idx];
  if (idx < n) cnt[idx] = 1;
  if (idx == 0) *total = 0;
}

// ---------------- CSR (by dst) build ----------------------------------
__global__ void count_edges2(const int* __restrict__ d0, const int* __restrict__ d1,
                             int* __restrict__ cnt) {
  const int i = blockIdx.x * blockDim.x + threadIdx.x;
  if (i < kE) atomicAdd(&cnt[d0[i]], 1);
  else if (i < 2 * kE) atomicAdd(&cnt[d1[i - kE] + kN], 1);
}
__global__ void fill_edges2(const int* __restrict__ s0, const int* __restrict__ d0,
                            const int* __restrict__ s1, const int* __restrict__ d1,
                            int* __restrict__ cursor, int* __restrict__ csr) {
  const int i = blockIdx.x * blockDim.x + threadIdx.x;
  if (i < kE) {
    const int p = atomicAdd(&cursor[d0[i]], 1);
    csr[p] = s0[i];
  } else if (i < 2 * kE) {
    const int j = i - kE;
    const int p = atomicAdd(&cursor[d1[j] + kN], 1);
    csr[p] = s1[j] + kN;
  }
}
__global__ void count_edges(const int* __restrict__ dst, int* __restrict__ cnt,
                            int ne) {
  const int i = blockIdx.x * blockDim.x + threadIdx.x;
  if (i < ne) atomicAdd(&cnt[dst[i]], 1);
}
__global__ void fill_edges(const int* __restrict__ src, const int* __restrict__ dst,
                           int* __restrict__ cursor, int* __restrict__ csr, int ne) {
  const int i = blockIdx.x * blockDim.x + threadIdx.x;
  if (i < ne) {
    const int p = atomicAdd(&cursor[dst[i]], 1);
    csr[p] = src[i];
  }
}
__global__ void alloc_ranges(const int* __restrict__ cnt, int* __restrict__ start,
                             int* __restrict__ cursor, int* __restrict__ total,
                             int* __restrict__ csr, int n) {
  const int i = blockIdx.x * blockDim.x + threadIdx.x;
  const int lane = threadIdx.x & 63;
  const int v = (i < n) ? cnt[i] : 0;
  int sc = v;
#pragma unroll
  for (int off = 1; off < 64; off <<= 1) {
    const int t = __shfl_up(sc, off);
    if (lane >= off) sc += t;
  }
  const int wtot = __shfl(sc, 63);
  int base = 0;
  if (lane == 63) base = atomicAdd(total, wtot);
  base = __shfl(base, 63);
  const int st = base + sc - v;
  if (i < n) {
    start[i] = st;
    cursor[i] = st + 1;
    csr[st] = i;  // self loop first
  }
}

// ---------------- GAT aggregate, layers 1-2 (f16 h) -------------------
// Attention dots fused in: <h[src],a_src> from the gathered fragment
// (8 FMA + 4 shfl_xor in the 16-lane head group); <h[node],a_dst> from
// the self-loop gather (CSR entry 0).
__global__ void gat_agg4(const _Float16* __restrict__ h,
                         const float* __restrict__ a_src,
                         const float* __restrict__ a_dst,
                         const int* __restrict__ start, const int* __restrict__ cnt,
                         const int* __restrict__ csr_src,
                         const float* __restrict__ bias,
                         _Float16* __restrict__ outH, int n_nodes) {
  const int gtid = blockIdx.x * blockDim.x + threadIdx.x;
  const int node = gtid >> 6;
  const int lane = threadIdx.x & 63;
  if (node >= n_nodes) return;
  const int ch = lane * 8;
  float as_r[8], ad_r[8];
#pragma unroll
  for (int j = 0; j < 8; ++j) {
    as_r[j] = a_src[ch + j];
    ad_r[j] = a_dst[ch + j];
  }
  const int s = start[node];
  const int c = cnt[node];
  // self loop first (csr_src[s] == node): gives both dst-dot and its edge
  const half8 vs = *(const half8*)(h + (size_t)node * 512 + ch);
  float fs[8];
  float t_src = 0.f, t_dst = 0.f;
#pragma unroll
  for (int j = 0; j < 8; ++j) {
    fs[j] = (float)vs[j];
    t_src = fmaf(fs[j], as_r[j], t_src);
    t_dst = fmaf(fs[j], ad_r[j], t_dst);
  }
#pragma unroll
  for (int off = 1; off < 16; off <<= 1) {
    t_src += __shfl_xor(t_src, off);
    t_dst += __shfl_xor(t_dst, off);
  }
  const float ad = t_dst;  // <h[node], a_dst> for this head
  float es = t_src + ad;
  es = (es > 0.f) ? es : kNegSlope * es;
  const float ws = fexp(es);
  float d0 = ws, d1 = 0.f;
  float a0[8], a1[8];
#pragma unroll
  for (int j = 0; j < 8; ++j) {
    a0[j] = ws * fs[j];
    a1[j] = 0.f;
  }
  int i = 1;
  for (; i + 2 <= c; i += 2) {
    const int s0 = csr_src[s + i];
    const int s1 = csr_src[s + i + 1];
    const half8 v0 = *(const half8*)(h + (size_t)s0 * 512 + ch);
    const half8 v1 = *(const half8*)(h + (size_t)s1 * 512 + ch);
    float f0[8], f1[8];
    float t0 = 0.f, t1 = 0.f;
#pragma unroll
    for (int j = 0; j < 8; ++j) {
      f0[j] = (float)v0[j];
      f1[j] = (float)v1[j];
      t0 = fmaf(f0[j], as_r[j], t0);
      t1 = fmaf(f1[j], as_r[j], t1);
    }
#pragma unroll
    for (int off = 1; off < 16; off <<= 1) {
      t0 += __shfl_xor(t0, off);
      t1 += __shfl_xor(t1, off);
    }
    float e0 = t0 + ad;
    float e1 = t1 + ad;
    e0 = (e0 > 0.f) ? e0 : kNegSlope * e0;
    e1 = (e1 > 0.f) ? e1 : kNegSlope * e1;
    const float w0 = fexp(e0);
    const float w1 = fexp(e1);
    d0 += w0;
    d1 += w1;
#pragma unroll
    for (int j = 0; j < 8; ++j) {
      a0[j] = fmaf(w0, f0[j], a0[j]);
      a1[j] = fmaf(w1, f1[j], a1[j]);
    }
  }
  if (i < c) {
    const int s0 = csr_src[s + i];
    const half8 v0 = *(const half8*)(h + (size_t)s0 * 512 + ch);
    float f0[8];
    float t0 = 0.f;
#pragma unroll
    for (int j = 0; j < 8; ++j) {
      f0[j] = (float)v0[j];
      t0 = fmaf(f0[j], as_r[j], t0);
    }
#pragma unroll
    for (int off = 1; off < 16; off <<= 1) t0 += __shfl_xor(t0, off);
    float e0 = t0 + ad;
    e0 = (e0 > 0.f) ? e0 : kNegSlope * e0;
    const float w0 = fexp(e0);
    d0 += w0;
#pragma unroll
    for (int j = 0; j < 8; ++j) a0[j] = fmaf(w0, f0[j], a0[j]);
  }
  const float inv = 1.f / (d0 + d1 + 1e-16f);
  half8 H;
#pragma unroll
  for (int j = 0; j < 8; ++j) {
    float v = (a0[j] + a1[j]) * inv + bias[ch + j];
    v = (v > 0.f) ? v : (fexp(v) - 1.f);  // elu via hw exp
    H[j] = (_Float16)v;
  }
  *(half8*)(outH + (size_t)node * 512 + ch) = H;
}

// ---------- GAT aggregate, layer 3 (H=1, fp32, fused dots) ------------
__global__ void gat_agg_l3(const float* __restrict__ h,
                           const float* __restrict__ a_src,
                           const float* __restrict__ a_dst,
                           const int* __restrict__ start, const int* __restrict__ cnt,
                           const int* __restrict__ csr_src,
                           const float* __restrict__ bias,
                           float* __restrict__ out, int n_nodes) {
  const int gtid = blockIdx.x * blockDim.x + threadIdx.x;
  const int node = gtid >> 6;
  const int lane = threadIdx.x & 63;
  if (node >= n_nodes) return;
  const float2 asv = *(const float2*)(a_src + lane * 2);
  const float2 adv = *(const float2*)(a_dst + lane * 2);
  const int s = start[node];
  const int c = cnt[node];
  // self loop first: dst-dot + its own edge
  const float2 vs = *(const float2*)(h + (size_t)node * 128 + lane * 2);
  float t_src = fmaf(vs.x, asv.x, vs.y * asv.y);
  float t_dst = fmaf(vs.x, adv.x, vs.y * adv.y);
#pragma unroll
  for (int off = 1; off < 64; off <<= 1) {
    t_src += __shfl_xor(t_src, off);
    t_dst += __shfl_xor(t_dst, off);
  }
  const float ad = t_dst;
  float es = t_src + ad;
  es = (es > 0.f) ? es : kNegSlope * es;
  const float ws = fexp(es);
  float2 a0 = make_float2(ws * vs.x, ws * vs.y);
  float2 a1 = make_float2(0.f, 0.f);
  float d0 = ws, d1 = 0.f;
  int i = 1;
  for (; i + 2 <= c; i += 2) {
    const int s0 = csr_src[s + i];
    const int s1 = csr_src[s + i + 1];
    const float2 v0 = *(const float2*)(h + (size_t)s0 * 128 + lane * 2);
    const float2 v1 = *(const float2*)(h + (size_t)s1 * 128 + lane * 2);
    float t0 = fmaf(v0.x, asv.x, v0.y * asv.y);
    float t1 = fmaf(v1.x, asv.x, v1.y * asv.y);
#pragma unroll
    for (int off = 1; off < 64; off <<= 1) {
      t0 += __shfl_xor(t0, off);
      t1 += __shfl_xor(t1, off);
    }
    float e0 = t0 + ad;
    float e1 = t1 + ad;
    e0 = (e0 > 0.f) ? e0 : kNegSlope * e0;
    e1 = (e1 > 0.f) ? e1 : kNegSlope * e1;
    const float w0 = fexp(e0);
    const float w1 = fexp(e1);
    d0 += w0;
    d1 += w1;
    a0.x = fmaf(w0, v0.x, a0.x); a1.x = fmaf(w1, v1.x, a1.x);
    a0.y = fmaf(w0, v0.y, a0.y); a1.y = fmaf(w1, v1.y, a1.y);
  }
  if (i < c) {
    const int s0 = csr_src[s + i];
    const float2 v0 = *(const float2*)(h + (size_t)s0 * 128 + lane * 2);
    float t0 = fmaf(v0.x, asv.x, v0.y * asv.y);
#pragma unroll
    for (int off = 1; off < 64; off <<= 1) t0 += __shfl_xor(t0, off);
    float e0 = t0 + ad;
    e0 = (e0 > 0.f) ? e0 : kNegSlope * e0;
    const float w0 = fexp(e0);
    d0 += w0;
    a0.x = fmaf(w0, v0.x, a0.x);
    a0.y = fmaf(w0, v0.y, a0.y);
  }
  const float inv = 1.f / (d0 + d1 + 1e-16f);
  *(float2*)(out + (size_t)node * 128 + lane * 2) =
      make_float2((a0.x + a1.x) * inv + bias[lane * 2],
                  (a0.y + a1.y) * inv + bias[lane * 2 + 1]);
}

// ------- global max pool over sorted batch (both encoders, 1 launch) ---
__global__ void pool_max2(const float* __restrict__ x, const int* __restrict__ bt1,
                          const int* __restrict__ bt2, float* __restrict__ emb) {
  __shared__ int lohi[2];
  const int enc = blockIdx.x >> 8;
  const int g = blockIdx.x & 255;
  const int* batch = enc ? bt2 : bt1;
  const float* xx = x + (size_t)enc * kN * 128;
  if (threadIdx.x == 0) {
    int lo = 0, hi = kN;
    while (lo < hi) {
      const int mid = (lo + hi) >> 1;
      if (batch[mid] < g) lo = mid + 1; else hi = mid;
    }
    lohi[0] = lo;
    hi = kN;
    while (lo < hi) {
      const int mid = (lo + hi) >> 1;
      if (batch[mid] < g + 1) lo = mid + 1; else hi = mid;
    }
    lohi[1] = lo;
  }
  __syncthreads();
  const int lo = lohi[0], hi = lohi[1];
  const int c = threadIdx.x;  // 128 channels
  float m = -1e30f;
  for (int nid = lo; nid < hi; ++nid) m = fmaxf(m, xx[(size_t)nid * 128 + c]);
  emb[(size_t)blockIdx.x * 128 + c] = (lo < hi) ? m : 0.f;
}
// ------- single-encoder pool (fallback path) --------------------------
__global__ void pool_max(const float* __restrict__ x, const int* __restrict__ batch,
                         float* __restrict__ emb, int n_nodes) {
  __shared__ int lohi[2];
  const int g = blockIdx.x;
  if (threadIdx.x == 0) {
    int lo = 0, hi = n_nodes;
    while (lo < hi) {
      const int mid = (lo + hi) >> 1;
      if (batch[mid] < g) lo = mid + 1; else hi = mid;
    }
    lohi[0] = lo;
    hi = n_nodes;
    while (lo < hi) {
      const int mid = (lo + hi) >> 1;
      if (batch[mid] < g + 1) lo = mid + 1; else hi = mid;
    }
    lohi[1] = lo;
  }
  __syncthreads();
  const int lo = lohi[0], hi = lohi[1];
  const int c = threadIdx.x;  // 128 channels
  float m = -1e30f;
  for (int nid = lo; nid < hi; ++nid) m = fmaxf(m, x[(size_t)nid * 128 + c]);
  emb[g * 128 + c] = (lo < hi) ? m : 0.f;
}

// ---------------- final MLP head --------------------------------------
__global__ void mlp_head(const float* __restrict__ e1, const float* __restrict__ e2,
                         const float* __restrict__ mw1, const float* __restrict__ mb1,
                         const float* __restrict__ mw2, const float* __restrict__ mb2,
                         float* __restrict__ out) {
  __shared__ float z[256];
  __shared__ float red[128];
  const int g = blockIdx.x;
  const int j = threadIdx.x;  // 128
  z[j] = e1[g * 128 + j];
  z[j + 128] = e2[g * 128 + j];
  __syncthreads();
  float acc = mb1[j];
  for (int k = 0; k < 256; ++k) acc = fmaf(z[k], mw1[k * 128 + j], acc);
  acc = fmaxf(acc, 0.f) * mw2[j];
  red[j] = acc;
  __syncthreads();
  for (int s = 64; s > 0; s >>= 1) {
    if (j < s) red[j] += red[j + s];
    __syncthreads();
  }
  if (j == 0) out[g] = red[0] + mb2[0];
}

// ---------------- launcher --------------------------------------------
namespace {
struct Bufs {
  _Float16 *R1h, *R2h;
  float *R1f, *R2f, *asrc, *adst;
  int *cnt, *start, *cursor, *csr, *total;
  _Float16 *Wth1, *Wth2, *Wth3;
  float* emb;
  size_t need;
};

Bufs plan(void* d_ws, int M, int E) {
  Bufs b;
  char* w = (char*)d_ws;
  size_t off = 0;
  auto take = [&](size_t bytes) -> void* {
    void* p = w + off;
    off += (bytes + 255) & ~(size_t)255;
    return p;
  };
  b.R1h = (_Float16*)take((size_t)M * 512 * 2);  // f16 activations
  b.R1f = (float*)b.R1h;                         // layer-3 out alias [M,128]
  b.R2h = (_Float16*)take((size_t)M * 512 * 2);  // h f16; l3 fp32 alias
  b.R2f = (float*)b.R2h;
  b.asrc = (float*)take((size_t)M * 4 * 4);      // (unused since fusion)
  b.adst = (float*)take((size_t)M * 4 * 4);
  b.cnt = (int*)take((size_t)M * 4);
  b.start = (int*)take((size_t)M * 4);
  b.cursor = (int*)take((size_t)M * 4);
  b.csr = (int*)take((size_t)E * 4);
  b.total = (int*)take(256);
  b.Wth1 = (_Float16*)take((size_t)64 * 512 * 2);
  b.Wth2 = (_Float16*)take((size_t)512 * 512 * 2);
  b.Wth3 = (_Float16*)take((size_t)512 * 128 * 2);
  b.emb = (float*)take((size_t)2 * kG * 128 * 4);
  b.need = off;
  return b;
}

void run_layers(const Bufs& b, void* const* d_in, int M, hipStream_t stream) {
  const float* as1 = (const float*)d_in[7];
  const float* ad1 = (const float*)d_in[8];
  const float* b1 = (const float*)d_in[9];
  const float* as2 = (const float*)d_in[11];
  const float* ad2 = (const float*)d_in[12];
  const float* b2 = (const float*)d_in[13];
  const float* as3 = (const float*)d_in[15];
  const float* ad3 = (const float*)d_in[16];
  const float* b3 = (const float*)d_in[17];
  const int nodeBlocks = (M * 64) / 256;  // 1 wave/node
  const int MT = (M + 255) / 256;         // 256-row tiles
  const int SP = (MT + 7) / 8;            // row-tile groups of 8 (XCD map)

  // layer 1: [M,64] @ [64,512], h -> f16 (A1h aliases R1h)
  gemm_ring<1, 256, 2><<<SP * 16, 512, 0, stream>>>(b.R1h, b.Wth1, b.R2h, M, 512, 64);
  gat_agg4<<<nodeBlocks, 256, 0, stream>>>(b.R2h, as1, ad1, b.start, b.cnt,
                                           b.csr, b1, b.R1h, M);
  // layer 2: [M,512] @ [512,512], h -> f16
  gemm_ring<1, 256, 2><<<SP * 16, 512, 0, stream>>>(b.R1h, b.Wth2, b.R2h, M, 512, 512);
  gat_agg4<<<nodeBlocks, 256, 0, stream>>>(b.R2h, as2, ad2, b.start, b.cnt,
                                           b.csr, b2, b.R1h, M);
  // layer 3: [M,512] @ [512,128], H=1, no elu, fp32 out
  gemm_ring<0, 128, 1><<<SP * 8, 512, 0, stream>>>(b.R1h, b.Wth3, b.R2f, M, 128, 512);
  gat_agg_l3<<<nodeBlocks, 256, 0, stream>>>(b.R2f, as3, ad3, b.start, b.cnt,
                                             b.csr, b3, b.R1f, M);
}
}  // namespace

extern "C" void kernel_launch(void* const* d_in, const int* in_sizes, int n_in,
                              void* d_out, int out_size, void* d_ws, size_t ws_size,
                              hipStream_t stream) {
  (void)in_sizes; (void)n_in; (void)out_size;
  const float* W1 = (const float*)d_in[6];
  const float* W2 = (const float*)d_in[10];
  const float* W3 = (const float*)d_in[14];
  const float* mw1 = (const float*)d_in[18];
  const float* mb1 = (const float*)d_in[19];
  const float* mw2 = (const float*)d_in[20];
  const float* mb2 = (const float*)d_in[21];

  // Prefer combined (both encoders batched, M=2N) if it fits the workspace.
  Bufs bc = plan(d_ws, 2 * kN, 2 * kE2);
  const bool combined = bc.need <= ws_size;
  Bufs b = combined ? bc : plan(d_ws, kN, kE2);

  const int wtot = 64 * 512 + 512 * 512 + 512 * 128;
  wt_split_all<<<(wtot + 255) / 256, 256, 0, stream>>>(W1, b.Wth1, W2, b.Wth2, W3,
                                                       b.Wth3);
  if (combined) {
    const int M = 2 * kN;
    const int* ei0 = (const int*)d_in[1];
    const int* ei1 = (const int*)d_in[4];
    prep2<<<(2 * kN * 64 + 255) / 256, 256, 0, stream>>>(
        (const float*)d_in[0], (const float*)d_in[3], b.R1h, b.cnt, b.total);
    count_edges2<<<(2 * kE + 255) / 256, 256, 0, stream>>>(ei0 + kE, ei1 + kE,
                                                           b.cnt);
    alloc_ranges<<<(M + 255) / 256, 256, 0, stream>>>(b.cnt, b.start, b.cursor,
                                                      b.total, b.csr, M);
    fill_edges2<<<(2 * kE + 255) / 256, 256, 0, stream>>>(ei0, ei0 + kE, ei1,
                                                          ei1 + kE, b.cursor, b.csr);
    run_layers(b, d_in, M, stream);
    pool_max2<<<2 * kG, 128, 0, stream>>>(b.R1f, (const int*)d_in[2],
                                          (const int*)d_in[5], b.emb);
  } else {
    for (int enc = 0; enc < 2; ++enc) {
      const float* x = (const float*)d_in[enc * 3 + 0];
      const int* ei = (const int*)d_in[enc * 3 + 1];
      const int* batch = (const int*)d_in[enc * 3 + 2];
      prep<<<(kN * 64 + 255) / 256, 256, 0, stream>>>(x, b.R1h, b.cnt, b.total,
                                                      kN * 64, kN);
      count_edges<<<(kE + 255) / 256, 256, 0, stream>>>(ei + kE, b.cnt, kE);
      alloc_ranges<<<(kN + 255) / 256, 256, 0, stream>>>(b.cnt, b.start, b.cursor,
                                                         b.total, b.csr, kN);
      fill_edges<<<(kE + 255) / 256, 256, 0, stream>>>(ei, ei + kE, b.cursor, b.csr,
                                                       kE);
      run_layers(b, d_in, kN, stream);
      pool_max<<<kG, 128, 0, stream>>>(b.R1f, batch, b.emb + (size_t)enc * kG * 128,
                                       kN);
    }
  }
  mlp_head<<<kG, 128, 0, stream>>>(b.emb, b.emb + (size_t)kG * 128, mw1, mb1, mw2,
                                   mb2, (float*)d_out);
}